// Round 12
// baseline (152.952 us; speedup 1.0000x reference)
//
#include <hip/hip_runtime.h>

#define HDIM   64
#define TSTEPS 5
#define WAVES  8
#define BLOCK  (WAVES * 64)     // 512 threads
#define EPW    16               // batch per wave = MFMA M
#define EPB    (WAVES * EPW)    // 128 batch per block

typedef _Float16 f16x8 __attribute__((ext_vector_type(8)));
typedef float    f32x4 __attribute__((ext_vector_type(4)));

#define L2E 1.44269504088896340736f   // log2(e)

// Native 1-ulp ops (trans pipe -> minimize count; floor is 5 ex2 + 2 rcp per u)
__device__ __forceinline__ float rcp_(float x) { return __builtin_amdgcn_rcpf(x); }
__device__ __forceinline__ float ex2_(float x) { return __builtin_amdgcn_exp2f(x); }

// ===== FINAL KERNEL: round-8 configuration, verified best =====
// rocprof 103.9 us, bench 150.6 us, VGPR 60, zero scratch, absmax 9.77e-4.
//
// Gates as D[m=batch e][n=gate row j'] = A[e][k]*B[k][j'] + C(bias + x*W_ih)
// A = h^T (rebuilt per t), B = W_hh^T (staged once, PRE-SCALED by log2e /
// 2*log2e for g columns). 16x16x32 f16 layouts (verified, absmax 9.8e-4):
//   A-frag: lane holds A[m=lane&15][k = kh*32 + (lane>>4)*8 + i], i=0..7
//   B-frag: lane holds B[k = kh*32 + (lane>>4)*8 + i][n = ntile*16 + (lane&15)]
//   C/D:    lane holds D[m = (lane>>4)*4 + reg][n = ntile*16 + (lane&15)]
//
// ACTIVATION (7 trans/u, floor for this functional form):
//   a  = (1+Ei)(Eg+1);  b = (1+Ef);  rr = rcp(a*b)       // ONE rcp for i&f
//   it = 2L2E*(Eg-1)*(rr*b); sf = rr*a; cs = fmaf(sf,c,it)  [2L2E-scaled c]
//   hn = (Ec-1)*rcp((1+Eo)(Ec+1))                        // o*tanh(c), ONE rcp
// hv[16] eliminated: FC accumulated inline at t=4 (W_fc in LDS).
//
// CONSTRAINT WEB — every branch measured and closed (rounds 1-11):
//   VGPR cap = 256/arg2 (8->32, 4->64, 3->85, 2->128). arg2=4 is OPTIMAL:
//   it is the spill guard AND the better schedule (arg2=3 with identical
//   VGPR=60 regressed 104->111 us: waves-per-eu also steers the scheduler).
//   Residency cliff AT 64 VGPR (r6: VGPR 64 -> 4 waves/SIMD, 119 us).
//   DEAD: WAVES=16 (cliff, r1/r6); global common-denominator activation
//   (live ~95, spills: r2/3/5); hoisted coeff arrays (+32 live, r3);
//   TRANSPOSED gates^T=W_hh*h^T (live ~68-75, spills: r9/r10); per-gr
//   sched_barriers (r7, -5%); trans cuts beyond 7/u (issue-neutral);
//   arg2=3 scheduler hint (r11, -7%).
//   Remaining 23% VALU-idle = dependency stall, fillable only by more waves
//   (needs VGPR<=63 AND LDS<=40KB simultaneously — structurally unreachable)
//   or more ILP (needs regs past the cliff). This is the structural floor.
__global__ __launch_bounds__(BLOCK, 4) void lstm_mfma_kernel(
    const float* __restrict__ x,      // [B, T, 1]
    const float* __restrict__ W_ih,   // [256, 1]
    const float* __restrict__ W_hh,   // [256, 64]
    const float* __restrict__ b_ih,   // [256]
    const float* __restrict__ b_hh,   // [256]
    const float* __restrict__ W_fc,   // [1, 64]
    const float* __restrict__ b_fc,   // [1]
    float* __restrict__ out,          // [B, 1]
    int B)
{
    __shared__ _Float16 Wf[2048 * 8];          // 32 KB, B-fragments, fragment-linear
    __shared__ _Float16 hbuf[WAVES * 1024];    // 16 KB, per-wave h A-fragments
    __shared__ float    wih_s[256];            // 1 KB (pre-scaled)
    __shared__ float    cb_s[256];             // 1 KB (pre-scaled b_ih + b_hh)
    __shared__ float    wfc_s[64];             // 256 B (FC weights)

    const int tid = threadIdx.x;

    // ---- one-time staging: W_hh -> fp16 B-fragments, log2e pre-scaled ----
    #pragma unroll
    for (int s0 = 0; s0 < 2048; s0 += BLOCK) {
        const int s  = s0 + tid;
        const int ln = s & 63;
        const int kh = (s >> 6) & 1;
        const int n  = s >> 7;                             // N-tile 0..15, gate G = n>>2
        const float scl = ((n >> 2) == 2) ? (2.0f * L2E) : L2E;
        const int j  = n * 16 + (ln & 15);                 // gate row j'
        const int k0 = kh * 32 + ((ln >> 4) & 3) * 8;      // hidden k
        const float* src = W_hh + j * HDIM + k0;
        #pragma unroll
        for (int i = 0; i < 8; i++)
            Wf[s * 8 + i] = (_Float16)(src[i] * scl);
    }
    if (tid < 256) {
        const float scl = ((tid >> 6) == 2) ? (2.0f * L2E) : L2E;
        wih_s[tid] = W_ih[tid] * scl;
        cb_s[tid]  = (b_ih[tid] + b_hh[tid]) * scl;
    }
    if (tid < 64) wfc_s[tid] = W_fc[tid];
    __syncthreads();   // only barrier in the kernel

    const int lane = tid & 63;
    const int wave = tid >> 6;
    const int m    = lane & 15;    // C-layout column (gate-row local) / A row m
    const int q    = lane >> 4;    // quad
    const int eg0  = (blockIdx.x * WAVES + wave) * EPW;

    _Float16* hb = hbuf + wave * 1024;

    // Single x base pointer; per-(r,t) loads are compile-time imm offsets.
    // Clamp the 4-row window into [0, B): rows >= B compute garbage on valid
    // memory; the out-write guard drops them.
    int e0 = eg0 + q * 4;
    if (e0 > B - 4) e0 = (B >= 4 ? B - 4 : 0);
    const float* xp0 = x + (long)e0 * TSTEPS;

    float c[16];    // cell state, SCALED by 2*log2e; [gr*4+r] <-> (j=gr*16+m, e=e0+r)
    float pfc[4];   // FC partial sums, defined only in the t=4 body

    #pragma unroll
    for (int t = 0; t < TSTEPS; t++) {
        float xt[4];
        #pragma unroll
        for (int r = 0; r < 4; r++) xt[r] = xp0[r * TSTEPS + t];   // imm offsets

        // h A-fragments from previous timestep (same-wave LDS, no barrier needed)
        f16x8 hA0, hA1;
        if (t > 0) {
            hA0 = *(const f16x8*)(hb + lane * 8);          // kh = 0
            hA1 = *(const f16x8*)(hb + 512 + lane * 8);    // kh = 1
        }

        #pragma unroll
        for (int gr = 0; gr < 4; gr++) {       // j' chunk: j = gr*16 + m
            // C-init: bias + x*W_ih directly as the MFMA C operand
            float wihv[4], cbv[4];
            #pragma unroll
            for (int G = 0; G < 4; G++) {
                wihv[G] = wih_s[G * 64 + gr * 16 + m];   // broadcast, conflict-free
                cbv[G]  = cb_s[G * 64 + gr * 16 + m];
            }
            f32x4 ag[4];
            #pragma unroll
            for (int G = 0; G < 4; G++)
                #pragma unroll
                for (int r = 0; r < 4; r++)
                    ag[G][r] = fmaf(xt[r], wihv[G], cbv[G]);

            if (t > 0) {
                #pragma unroll
                for (int G = 0; G < 4; G++) {
                    const int n = G * 4 + gr;
                    f16x8 w0 = *(const f16x8*)(Wf + (n * 2 + 0) * 512 + lane * 8);
                    f16x8 w1 = *(const f16x8*)(Wf + (n * 2 + 1) * 512 + lane * 8);
                    ag[G] = __builtin_amdgcn_mfma_f32_16x16x32_f16(hA0, w0, ag[G], 0, 0, 0);
                    ag[G] = __builtin_amdgcn_mfma_f32_16x16x32_f16(hA1, w1, ag[G], 0, 0, 0);
                }
            }

            #pragma unroll
            for (int r = 0; r < 4; r++) {
                const int u = gr * 4 + r;
                const float Ei = ex2_(-ag[0][r]);
                const float Eg = ex2_(ag[2][r]);
                const float a  = (1.0f + Ei) * (Eg + 1.0f);
                const float gn = (2.0f * L2E) * (Eg - 1.0f);
                float cs;
                if (t > 0) {
                    // paired rcp: one v_rcp serves both i*tanh(g) and sigmoid(f)
                    const float Ef = ex2_(-ag[1][r]);
                    const float b  = 1.0f + Ef;
                    const float rr = rcp_(a * b);
                    const float it = gn * (rr * b);
                    const float sf = rr * a;
                    cs = fmaf(sf, c[u], it);
                } else {
                    cs = gn * rcp_(a);
                }
                c[u] = cs;                                // scaled domain
                // fused o*tanh(c): 2 ex2 + 1 rcp
                const float Eo = ex2_(-ag[3][r]);
                const float Ec = ex2_(cs);
                const float hn = (Ec - 1.0f) * rcp_((1.0f + Eo) * (Ec + 1.0f));
                if (t < TSTEPS - 1) {
                    // scatter h (fp16) into next timestep's A-fragment slots
                    const int lp = (q * 4 + r) + 16 * (2 * (gr & 1) + (m >> 3));
                    hb[(gr >> 1) * 512 + lp * 8 + (m & 7)] = (_Float16)hn;
                } else {
                    // FC inline: pfc[r] += h[j=gr*16+m][e] * W_fc[j]
                    const float w = wfc_s[gr * 16 + m];
                    pfc[r] = (gr == 0) ? hn * w : fmaf(hn, w, pfc[r]);
                }
            }
        }
    }

    // ---- FC epilogue: reduce pfc over the 16 m-lanes, write out ----
    const float bfc = b_fc[0];
    #pragma unroll
    for (int r = 0; r < 4; r++) {
        float p = pfc[r];
        p += __shfl_xor(p, 1, 64);
        p += __shfl_xor(p, 2, 64);
        p += __shfl_xor(p, 4, 64);
        p += __shfl_xor(p, 8, 64);
        if (m == 0) {
            const int e = e0 + r;
            if (e < B) out[e] = p + bfc;
        }
    }
}

extern "C" void kernel_launch(void* const* d_in, const int* in_sizes, int n_in,
                              void* d_out, int out_size, void* d_ws, size_t ws_size,
                              hipStream_t stream) {
    const float* x    = (const float*)d_in[0];
    const float* W_ih = (const float*)d_in[1];
    const float* W_hh = (const float*)d_in[2];
    const float* b_ih = (const float*)d_in[3];
    const float* b_hh = (const float*)d_in[4];
    const float* W_fc = (const float*)d_in[5];
    const float* b_fc = (const float*)d_in[6];
    float* out = (float*)d_out;

    const int B = in_sizes[0] / TSTEPS;   // x is [B, T, 1]
    const int grid = (B + EPB - 1) / EPB;
    lstm_mfma_kernel<<<grid, BLOCK, 0, stream>>>(x, W_ih, W_hh, b_ih, b_hh,
                                                 W_fc, b_fc, out, B);
}